// Round 3
// baseline (18869.295 us; speedup 1.0000x reference)
//
#include <hip/hip_runtime.h>

// LSTM B=64 T=2048 D=H=256.
// wt_prep: WiT[j][d] = (f16)Wi[d][j] — one-time transpose for proj A-frags.
// lstm_proj: xg[t][bg8][1024j][8b] = x@W_i + bias (fp16, MFMA f16).
// lstm_recur: persistent scan, 8 blocks x 8 batch rows, 16 waves (1024 thr).
//   Wave wv owns gate-cols {g*256 + wv*16 + n} for all 4 gates: ALL W_h resident
//   as fp16 VGPR B-fragments (128 regs/wave). h double-buffered in LDS (fp16),
//   ONE raw barrier per step (s_waitcnt lgkmcnt(0); s_barrier — no vmcnt drain).
//   Batch row b lives at MFMA m-row pi(b)=(b&3)*4+(b>>2) so the 8 valid C rows
//   land in reg 0,1 of every quad -> 2 h-elements per lane, no idle lanes.
// MFMA f32_16x16x32_f16 layouts (verified rounds 1-2):
//   A[m=lane&15][k=(lane>>4)*8+jj+kt*32], B[k][n=lane&15], C row=(lane>>4)*4+reg, col=lane&15.

#define T_ALL 2048
#define NBATCH 64
#define HD 256
#define NG 1024
#define RB 8
#define HS_N ((size_t)NBATCH * T_ALL * HD)
#define HROW 262   // halfs per h row: 256 + 6 pad (131 dwords == 3 mod 32 -> <=2-way bank alias)

typedef _Float16 h8 __attribute__((ext_vector_type(8)));
typedef float f4 __attribute__((ext_vector_type(4)));

__device__ __forceinline__ float sigf(float x) {
  return __builtin_amdgcn_rcpf(1.f + __expf(-x));
}
__device__ __forceinline__ float tanh_f(float x) {
  return 2.f * __builtin_amdgcn_rcpf(1.f + __expf(-2.f * x)) - 1.f;
}

// ---------------- one-time weight transpose ----------------
__global__ void wt_prep(const float* __restrict__ Wi, _Float16* __restrict__ WiT) {
  const int d = blockIdx.x;       // 0..255
  const int j = threadIdx.x;      // 0..1023 (coalesced read of Wi row d)
  WiT[(size_t)j * HD + d] = (_Float16)Wi[(size_t)d * NG + j];
}

// ---------------- input projection: one block per timestep ----------------
__global__ __launch_bounds__(256, 2) void lstm_proj(
    const float* __restrict__ x, const _Float16* __restrict__ WiT,
    const float* __restrict__ bias, _Float16* __restrict__ xg, int t0)
{
  const int t = t0 + blockIdx.x;
  const int tid = threadIdx.x;
  const int w = tid >> 6, L = tid & 63;
  const int n = L & 15, quad = L >> 4;

  // B-fragments: x^T[k][b], reused across all j tiles (32 frags = 128 VGPRs)
  h8 bx[8][4];
#pragma unroll
  for (int kt = 0; kt < 8; ++kt) {
#pragma unroll
    for (int bt = 0; bt < 4; ++bt) {
      const int b = bt * 16 + n, k = kt * 32 + quad * 8;
      const float* p = x + ((size_t)b * T_ALL + t) * HD + k;
      f4 lo = *(const f4*)p, hi = *(const f4*)(p + 4);
      h8 f;
      f[0] = (_Float16)lo[0]; f[1] = (_Float16)lo[1];
      f[2] = (_Float16)lo[2]; f[3] = (_Float16)lo[3];
      f[4] = (_Float16)hi[0]; f[5] = (_Float16)hi[1];
      f[6] = (_Float16)hi[2]; f[7] = (_Float16)hi[3];
      bx[kt][bt] = f;
    }
  }

  for (int i = 0; i < 16; ++i) {       // wave w owns j-tiles w*16 .. w*16+15
    const int jt = w * 16 + i;
    float bv0 = bias[jt * 16 + quad * 4 + 0];
    float bv1 = bias[jt * 16 + quad * 4 + 1];
    float bv2 = bias[jt * 16 + quad * 4 + 2];
    float bv3 = bias[jt * 16 + quad * 4 + 3];
    f4 acc[4];
#pragma unroll
    for (int bt = 0; bt < 4; ++bt) {
      acc[bt][0] = bv0; acc[bt][1] = bv1; acc[bt][2] = bv2; acc[bt][3] = bv3;
    }
#pragma unroll
    for (int kt = 0; kt < 8; ++kt) {
      const int j = jt * 16 + n, kb = kt * 32 + quad * 8;
      h8 a = *(const h8*)(WiT + (size_t)j * HD + kb);   // A[m=j][k=d], one b128
#pragma unroll
      for (int bt = 0; bt < 4; ++bt)
        acc[bt] = __builtin_amdgcn_mfma_f32_16x16x32_f16(a, bx[kt][bt], acc[bt], 0, 0, 0);
    }
#pragma unroll
    for (int bt = 0; bt < 4; ++bt) {
#pragma unroll
      for (int r = 0; r < 4; ++r) {
        const int j = jt * 16 + quad * 4 + r;          // gate col
        const int b = bt * 16 + n;
        xg[(((size_t)blockIdx.x * 8 + (b >> 3)) * NG + j) * 8 + (b & 7)] = (_Float16)acc[bt][r];
      }
    }
  }
}

// ---------------- one LSTM step (CUR = h read buffer) ----------------
template <int CUR>
__device__ __forceinline__ void lstm_step(
    _Float16 hbuf[2][16 * HROW], const h8 bW[4][8],
    const _Float16* __restrict__ xgp, const int voff[8],
    float creg[2], float* __restrict__ out_t, const int oidx[2],
    int n, int quad, int col)
{
  _Float16 xv[8];
#pragma unroll
  for (int k = 0; k < 8; ++k) xv[k] = xgp[voff[k]];

  f4 acc[4];
#pragma unroll
  for (int g = 0; g < 4; ++g) { acc[g][0] = 0.f; acc[g][1] = 0.f; acc[g][2] = 0.f; acc[g][3] = 0.f; }

#pragma unroll
  for (int kt = 0; kt < 8; ++kt) {
    h8 a = *(const h8*)(&hbuf[CUR][n * HROW + quad * 8 + kt * 32]);
#pragma unroll
    for (int g = 0; g < 4; ++g)
      acc[g] = __builtin_amdgcn_mfma_f32_16x16x32_f16(a, bW[g][kt], acc[g], 0, 0, 0);
  }

#pragma unroll
  for (int r = 0; r < 2; ++r) {
    const float vi = acc[0][r] + (float)xv[0 + r];
    const float vf = acc[1][r] + (float)xv[2 + r];
    const float vg = acc[2][r] + (float)xv[4 + r];
    const float vo = acc[3][r] + (float)xv[6 + r];
    const float cn = sigf(vf) * creg[r] + sigf(vi) * tanh_f(vg);
    const float hn = sigf(vo) * tanh_f(cn);
    creg[r] = cn;
    hbuf[CUR ^ 1][(quad * 4 + r) * HROW + col] = (_Float16)hn;
    out_t[oidx[r]] = hn;
  }
  // LDS-visibility-only barrier: do NOT drain vmcnt (global h stores fly on).
  __asm__ volatile("s_waitcnt lgkmcnt(0)\n\ts_barrier" ::: "memory");
}

// ---------------- persistent recurrence: 8 blocks x 8 batch rows ----------------
__global__ __launch_bounds__(1024, 4) void lstm_recur(
    const _Float16* __restrict__ xg, const float* __restrict__ Wh,
    float* __restrict__ out, _Float16* __restrict__ ws_h, float* __restrict__ ws_c,
    int t0, int CT)
{
  __shared__ _Float16 hbuf[2][16 * HROW];
  const int tid = threadIdx.x;
  const int wv = tid >> 6, L = tid & 63;
  const int n = L & 15, quad = L >> 4;
  const int b_base = blockIdx.x * RB;
  const int col = wv * 16 + n;

  // resident W_h: wave wv holds col-tile wv of every gate, fp16, 128 VGPRs
  h8 bW[4][8];
#pragma unroll
  for (int g = 0; g < 4; ++g)
#pragma unroll
    for (int kt = 0; kt < 8; ++kt) {
      const int j = g * 256 + col, kb = kt * 32 + quad * 8;
      h8 f;
#pragma unroll
      for (int jj = 0; jj < 8; ++jj) f[jj] = (_Float16)Wh[(size_t)(kb + jj) * NG + j];
      bW[g][kt] = f;
    }

  // zero both h buffers (rows not in pi-image stay zero forever)
  for (int i = tid; i < 2 * 16 * HROW; i += 1024) (&hbuf[0][0])[i] = (_Float16)0.f;
  float creg[2] = {0.f, 0.f};
  __syncthreads();
  if (t0 != 0) {
    if (tid < 256) {
      const int r = tid >> 5, c = (tid & 31) * 8;
      const int m = (r & 3) * 4 + (r >> 2);            // pi(b)
      *(h8*)(&hbuf[0][m * HROW + c]) = *(const h8*)(ws_h + (size_t)(b_base + r) * HD + c);
    }
#pragma unroll
    for (int r = 0; r < 2; ++r)
      creg[r] = ws_c[(size_t)(b_base + r * 4 + quad) * HD + col];
    __syncthreads();
  }

  int voff[8], oidx[2];
#pragma unroll
  for (int g = 0; g < 4; ++g)
#pragma unroll
    for (int r = 0; r < 2; ++r)
      voff[g * 2 + r] = (g * 256 + col) * 8 + r * 4 + quad;  // xg[t][bg][j][8b]
#pragma unroll
  for (int r = 0; r < 2; ++r)
    oidx[r] = (b_base + r * 4 + quad) * (T_ALL * HD) + col;  // + t*HD via out_t

  const _Float16* xgp = xg + (size_t)blockIdx.x * (NG * RB);
  float* out_t = out + (size_t)t0 * HD;

#pragma unroll 1
  for (int tt = 0; tt < CT; tt += 2) {                 // CT is even (power of two >= 32)
    lstm_step<0>(hbuf, bW, xgp, voff, creg, out_t, oidx, n, quad, col);
    xgp += NG * NBATCH; out_t += HD;
    lstm_step<1>(hbuf, bW, xgp, voff, creg, out_t, oidx, n, quad, col);
    xgp += NG * NBATCH; out_t += HD;
  }

  // persist chunk state (final h is in buf0 since CT even; last step's barrier done)
  if (tid < 256) {
    const int r = tid >> 5, c = (tid & 31) * 8;
    const int m = (r & 3) * 4 + (r >> 2);
    *(h8*)(ws_h + (size_t)(b_base + r) * HD + c) = *(const h8*)(&hbuf[0][m * HROW + c]);
  }
#pragma unroll
  for (int r = 0; r < 2; ++r)
    ws_c[(size_t)(b_base + r * 4 + quad) * HD + col] = creg[r];

  if (t0 + CT == T_ALL) {                              // h_T, c_T
#pragma unroll
    for (int r = 0; r < 2; ++r) {
      const int b = b_base + r * 4 + quad, m = quad * 4 + r;
      out[HS_N + (size_t)b * HD + col] = (float)hbuf[0][m * HROW + col];
      out[HS_N + (size_t)NBATCH * HD + (size_t)b * HD + col] = creg[r];
    }
  }
}

extern "C" void kernel_launch(void* const* d_in, const int* in_sizes, int n_in,
                              void* d_out, int out_size, void* d_ws, size_t ws_size,
                              hipStream_t stream) {
  (void)in_sizes; (void)n_in; (void)out_size;
  const float* x    = (const float*)d_in[0];
  const float* Wi   = (const float*)d_in[1];
  const float* Wh   = (const float*)d_in[2];
  const float* bias = (const float*)d_in[3];
  float* out = (float*)d_out;

  // ws: [xg CT*1024*64 f16][WiT 1024*256 f16][ws_h 64*256 f16][ws_c 64*256 f32]
  const size_t fixed = 524288 + 32768 + 65536;
  int CT = T_ALL;
  while (CT > 32 && (size_t)CT * 131072 + fixed > ws_size) CT >>= 1;

  _Float16* xg   = (_Float16*)d_ws;
  _Float16* WiT  = (_Float16*)((char*)d_ws + (size_t)CT * 131072);
  _Float16* ws_h = (_Float16*)((char*)WiT + 524288);
  float*    ws_c = (float*)((char*)ws_h + 32768);

  wt_prep<<<dim3(HD), dim3(NG), 0, stream>>>(Wi, WiT);
  for (int t0 = 0; t0 < T_ALL; t0 += CT) {
    lstm_proj<<<dim3(CT), dim3(256), 0, stream>>>(x, WiT, bias, xg, t0);
    lstm_recur<<<dim3(8), dim3(1024), 0, stream>>>(xg, Wh, out, ws_h, ws_c, t0, CT);
  }
}